// Round 1
// baseline (5728.775 us; speedup 1.0000x reference)
//
#include <hip/hip_runtime.h>
#include <cstdint>
#include <cstddef>

typedef short short8 __attribute__((ext_vector_type(8)));
typedef float floatx4 __attribute__((ext_vector_type(4)));

static constexpr int TT = 256;   // time steps
static constexpr int BB = 256;   // batch
static constexpr int DD = 1024;  // hidden dim

__device__ __forceinline__ unsigned short f32_to_bf16(float f) {
  union { float f; unsigned int u; } v;
  v.f = f;
  unsigned int r = v.u + 0x7FFFu + ((v.u >> 16) & 1u);  // RNE
  return (unsigned short)(r >> 16);
}

// ---------------------------------------------------------------------------
// Kernel 1: convert Wx (= W[:, :1024]) AND Wh (= W[:, 1024:]) to bf16,
// transposed, in MFMA B-fragment order. Fragment block (kc, nb): 64 lanes x
// 8 bf16; value (lane, j) = Wsub[n = nb*16 + (lane&15)][k = kc*32 +
// (lane>>4)*8 + j]. Slots 0..131071 -> wxt, 131072..262143 -> wht.
// ---------------------------------------------------------------------------
__global__ void prep_w(const float* __restrict__ W,
                       unsigned short* __restrict__ wxt,
                       unsigned short* __restrict__ wht) {
  int s = blockIdx.x * 256 + threadIdx.x;   // 262144 slots
  int half = s >> 17;                       // 0: Wx, 1: Wh
  int ss = s & 131071;
  int lane = ss & 63;
  int blk = ss >> 6;                        // kc*64 + nb
  int nb = blk & 63;
  int kc = blk >> 6;
  int n = nb * 16 + (lane & 15);
  int k = kc * 32 + (lane >> 4) * 8;
  const float* src = W + (size_t)n * 2048 + half * 1024 + k;
  short8 v;
#pragma unroll
  for (int j = 0; j < 8; ++j) v[j] = (short)f32_to_bf16(src[j]);
  unsigned short* dst = half ? wht : wxt;
  *reinterpret_cast<short8*>(dst + (size_t)ss * 8) = v;
}

// ---------------------------------------------------------------------------
// Kernel 2 (unchanged): Z[b,t,d] = x[t,b,:] @ Wx[d,:] + bias[d] -> d_out.
// 128x128 tile, BK=32, 4 waves each computing 64x64 via 16x16x32 bf16 MFMA.
// ---------------------------------------------------------------------------
__global__ __launch_bounds__(256, 2) void gemm_z(
    const float* __restrict__ x, const unsigned short* __restrict__ wxt,
    const float* __restrict__ bias, float* __restrict__ out) {
  __shared__ unsigned short Alds[8 * 512];  // 8 KB, fragment-ordered
  __shared__ unsigned short Blds[8 * 512];  // 8 KB, fragment-ordered

  int tid = threadIdx.x;
  int bx = blockIdx.x;
  int mtile = bx & 511;                     // 512 m-tiles (M = 65536)
  int ntile = bx >> 9;                      // 8 n-tiles  (N = 1024)
  int m0 = mtile * 128;
  int lane = tid & 63, w = tid >> 6;
  int mw = (w & 1) * 64, nw = (w >> 1) * 64;

  const float4* xf4 = reinterpret_cast<const float4*>(x);
  floatx4 acc[4][4] = {};

  for (int kt = 0; kt < 32; ++kt) {
    __syncthreads();
    // --- stage A: 128 rows x 32 k fp32 -> bf16 fragment layout ---
#pragma unroll
    for (int i = 0; i < 4; ++i) {
      int idx = i * 256 + tid;              // 0..1023 over (m_loc:128, kk:8)
      int m_loc = idx >> 3;
      int kk = idx & 7;                     // float4 index within 32-k chunk
      float4 xv = xf4[(size_t)(m0 + m_loc) * 256 + kt * 8 + kk];
      int l = (kk >> 1) * 16 + (m_loc & 15);
      int off = (m_loc >> 4) * 512 + l * 8 + (kk & 1) * 4;
      ushort4 pk;
      pk.x = f32_to_bf16(xv.x);
      pk.y = f32_to_bf16(xv.y);
      pk.z = f32_to_bf16(xv.z);
      pk.w = f32_to_bf16(xv.w);
      *reinterpret_cast<ushort4*>(Alds + off) = pk;
    }
    // --- stage B: 8 fragment blocks of 1 KB, already bf16+swizzled ---
#pragma unroll
    for (int i = 0; i < 2; ++i) {
      int s = i * 256 + tid;
      int nb = s >> 6;
      int ln = s & 63;
      short8 v = *reinterpret_cast<const short8*>(
          wxt + ((size_t)(kt * 64 + ntile * 8 + nb) * 512 + ln * 8));
      *reinterpret_cast<short8*>(Blds + nb * 512 + ln * 8) = v;
    }
    __syncthreads();
    // --- compute: 16 MFMA per wave per K-tile ---
    int abase = (mw >> 4) * 512 + lane * 8;
    int bbase = (nw >> 4) * 512 + lane * 8;
    short8 bf[4];
#pragma unroll
    for (int nt = 0; nt < 4; ++nt)
      bf[nt] = *reinterpret_cast<const short8*>(Blds + bbase + nt * 512);
#pragma unroll
    for (int mt = 0; mt < 4; ++mt) {
      short8 af = *reinterpret_cast<const short8*>(Alds + abase + mt * 512);
#pragma unroll
      for (int nt = 0; nt < 4; ++nt)
        acc[mt][nt] =
            __builtin_amdgcn_mfma_f32_16x16x32_bf16(af, bf[nt], acc[mt][nt], 0, 0, 0);
    }
  }

  // --- epilogue: + bias, write Z to d_out[b*T*D + t*D + d] (m = t*B + b) ---
  int quad = lane >> 4;
#pragma unroll
  for (int nt = 0; nt < 4; ++nt) {
    int n = ntile * 128 + nw + nt * 16 + (lane & 15);
    float bv = bias[n];
#pragma unroll
    for (int mt = 0; mt < 4; ++mt) {
#pragma unroll
      for (int r = 0; r < 4; ++r) {
        int m = m0 + mw + mt * 16 + quad * 4 + r;
        int t = m >> 8;
        int b = m & 255;
        out[(size_t)b * (TT * DD) + (size_t)t * DD + n] = acc[mt][nt][r] + bv;
      }
    }
  }
}

// ---------------------------------------------------------------------------
// Kernel 3: batch-parallel recurrence — NO inter-workgroup sync.
// 16 wgs x 512 threads (8 waves). wg g owns batch rows [g*16, g*16+16) and
// computes ALL 1024 output dims; wave w handles dims [w*128, (w+1)*128).
// h (16x1024 bf16) lives in a double-buffered, XOR-swizzled LDS tile; the
// only per-step sync is __syncthreads(). Wh streams from L2 (2 MB bf16,
// fragment-ordered by prep_w, resident in the XCD's 4 MiB L2).
// Per step per wave: 32 ds_read_b128 (A) + 256 coalesced 16B Wh loads (B)
// + 256 MFMA 16x16x32. acc starts at 0; Z is added in the epilogue so the
// Z loads (issued first) hide under the MFMA phase.
// ---------------------------------------------------------------------------
__global__ __launch_bounds__(512, 1) void rnn_rec2(
    const unsigned short* __restrict__ wht, float* __restrict__ out) {
  __shared__ unsigned short hl[2][16 * 1024];  // 2 x 32 KB, swizzled

  int tid = threadIdx.x;
  int lane = tid & 63, w = tid >> 6;   // 8 waves
  int col = lane & 15, quad = lane >> 4;
  int b0 = blockIdx.x * 16;
  int xm = (col & 7) << 4;             // A-read swizzle mask (row = col)
  const short8* whs = reinterpret_cast<const short8*>(wht);

  for (int t = 0; t < TT; ++t) {
    // --- Z loads, issued early; consumed only in the epilogue ---
    size_t zbase = (size_t)(b0 + quad * 4) * (TT * DD) + (size_t)t * DD +
                   w * 128 + col;
    float z[8][4];
#pragma unroll
    for (int r = 0; r < 4; ++r)
#pragma unroll
      for (int nt = 0; nt < 8; ++nt)
        z[nt][r] = out[zbase + (size_t)r * (TT * DD) + nt * 16];

    floatx4 acc[8] = {};
    if (t > 0) {
      const char* hp =
          reinterpret_cast<const char*>(hl[(t & 1) ^ 1]) + col * 2048;
#pragma unroll 4
      for (int kc = 0; kc < 32; ++kc) {
        // A frag: h[row = col][k = kc*32 + quad*8 + j], swizzled
        short8 af = *reinterpret_cast<const short8*>(
            hp + (((kc * 64) + quad * 16) ^ xm));
        const short8* bv = whs + (size_t)(kc * 64 + w * 8) * 64 + lane;
#pragma unroll
        for (int nt = 0; nt < 8; ++nt)
          acc[nt] = __builtin_amdgcn_mfma_f32_16x16x32_bf16(af, bv[nt * 64],
                                                            acc[nt], 0, 0, 0);
      }
    }

    // --- epilogue: h = tanh(acc + Z); fp32 -> out, bf16 -> LDS (swizzled) ---
    char* hc = reinterpret_cast<char*>(hl[t & 1]);
#pragma unroll
    for (int nt = 0; nt < 8; ++nt) {
      int d2 = (w * 128 + nt * 16 + col) * 2;
#pragma unroll
      for (int r = 0; r < 4; ++r) {
        float v = tanhf(acc[nt][r] + z[nt][r]);
        out[zbase + (size_t)r * (TT * DD) + nt * 16] = v;
        int row = quad * 4 + r;
        *reinterpret_cast<unsigned short*>(
            hc + row * 2048 + (d2 ^ ((row & 7) << 4))) = f32_to_bf16(v);
      }
    }
    __syncthreads();  // hl[t&1] complete before step t+1 reads it
  }
}

extern "C" void kernel_launch(void* const* d_in, const int* in_sizes, int n_in,
                              void* d_out, int out_size, void* d_ws, size_t ws_size,
                              hipStream_t stream) {
  (void)in_sizes; (void)n_in; (void)out_size; (void)ws_size;
  const float* x = (const float*)d_in[0];
  const float* W = (const float*)d_in[1];
  const float* b = (const float*)d_in[2];
  float* out = (float*)d_out;
  char* ws = (char*)d_ws;

  unsigned short* wxt = (unsigned short*)ws;                        // 2 MB
  unsigned short* wht = (unsigned short*)(ws + (size_t)(2u << 20)); // 2 MB

  hipLaunchKernelGGL(prep_w, dim3(1024), dim3(256), 0, stream, W, wxt, wht);
  hipLaunchKernelGGL(gemm_z, dim3(4096), dim3(256), 0, stream, x, wxt, b, out);
  hipLaunchKernelGGL(rnn_rec2, dim3(16), dim3(512), 0, stream, wht, out);
}